// Round 1
// baseline (1058.407 us; speedup 1.0000x reference)
//
#include <hip/hip_runtime.h>
#include <hip/hip_bf16.h>
#include <math.h>

typedef __attribute__((ext_vector_type(8))) short short8;
typedef __attribute__((ext_vector_type(4))) float floatx4;
using bf16_t = __hip_bfloat16;

#define GLOAD16(gp, lp)                                                        \
  __builtin_amdgcn_global_load_lds(                                            \
      (const __attribute__((address_space(1))) unsigned int*)(gp),             \
      (__attribute__((address_space(3))) unsigned int*)(lp), 16, 0, 0)

// ---------------------------------------------------------------- converts --
__global__ void convert_f32_to_bf16(const float* __restrict__ in,
                                    bf16_t* __restrict__ out) {
  int i = blockIdx.x * 256 + threadIdx.x;       // 4 elements per thread
  float4 v = ((const float4*)in)[i];
  union { ushort4 u; bf16_t b[4]; } pk;
  pk.b[0] = __float2bfloat16(v.x);
  pk.b[1] = __float2bfloat16(v.y);
  pk.b[2] = __float2bfloat16(v.z);
  pk.b[3] = __float2bfloat16(v.w);
  ((ushort4*)out)[i] = pk.u;
}

// out[c][r] = bf16(in[r][c]), both 4096x4096
template <typename T>
__global__ void transpose_to_bf16(const T* __restrict__ in,
                                  bf16_t* __restrict__ out) {
  __shared__ float tile[64][65];
  const int r0 = blockIdx.y * 64, c0 = blockIdx.x * 64;
  const int tid = threadIdx.x;
  for (int i = tid; i < 64 * 64; i += 256) {
    const int r = i >> 6, c = i & 63;
    float v;
    if constexpr (sizeof(T) == 4)
      v = in[(size_t)(r0 + r) * 4096 + (c0 + c)];
    else
      v = __bfloat162float(in[(size_t)(r0 + r) * 4096 + (c0 + c)]);
    tile[r][c] = v;
  }
  __syncthreads();
  for (int i = tid; i < 64 * 64; i += 256) {
    const int c = i >> 6, r = i & 63;
    out[(size_t)(c0 + c) * 4096 + (r0 + r)] = __float2bfloat16(tile[r][c]);
  }
}

// ---------------------------------------------------------------- NT GEMM ---
// C[m][n] = sum_k A[m][k] * B[n][k], all 4096x4096, A/B bf16 K-fastest.
// EPI 0: C=bf16(acc)
// EPI 1: C=bf16(relu(acc)*mask[m])
// EPI 2: C=bf16(X0[m][n] + relu(acc)*mask[m])
// EPI 3: Cf=float( satt[m] * relu(acc+lnb[n]) * mask[m] )
template <int EPI>
__global__ __launch_bounds__(256) void gemm_nt(
    const bf16_t* __restrict__ A, const bf16_t* __restrict__ B,
    void* __restrict__ C, const bf16_t* __restrict__ X0,
    const float* __restrict__ rowm, const float* __restrict__ satt,
    const float* __restrict__ lnb) {
  constexpr int LD = 4096;
  __shared__ bf16_t At[128 * 32];
  __shared__ bf16_t Bt[128 * 32];
  const int tid = threadIdx.x;
  const int wave = tid >> 6, lane = tid & 63;
  const int m0 = blockIdx.y * 128, n0 = blockIdx.x * 128;
  const int wm = (wave >> 1) * 64, wn = (wave & 1) * 64;

  floatx4 acc[4][4] = {};

  // staging geometry: 8 chunks of 512 elems (= 64 lanes x 8 bf16 = 1KB)
  const int chunk0 = wave;          // issue 0
  const int chunk1 = 4 + wave;      // issue 1
  const int e0 = chunk0 * 512 + lane * 8;
  const int e1 = chunk1 * 512 + lane * 8;
  const int mA0 = e0 >> 5, kA0 = e0 & 31;
  const int mA1 = e1 >> 5, kA1 = e1 & 31;
  bf16_t* lA0 = At + chunk0 * 512;
  bf16_t* lA1 = At + chunk1 * 512;
  bf16_t* lB0 = Bt + chunk0 * 512;
  bf16_t* lB1 = Bt + chunk1 * 512;

  for (int k0 = 0; k0 < 4096; k0 += 32) {
    GLOAD16(A + (size_t)(m0 + mA0) * LD + (k0 + kA0), lA0);
    GLOAD16(A + (size_t)(m0 + mA1) * LD + (k0 + kA1), lA1);
    GLOAD16(B + (size_t)(n0 + mA0) * LD + (k0 + kA0), lB0);
    GLOAD16(B + (size_t)(n0 + mA1) * LD + (k0 + kA1), lB1);
    __syncthreads();

    short8 af[4], bfr[4];
    const int rbase = lane & 15;
    const int kb = (lane >> 4) * 8;
#pragma unroll
    for (int f = 0; f < 4; ++f) {
      af[f]  = *(const short8*)(At + (wm + f * 16 + rbase) * 32 + kb);
      bfr[f] = *(const short8*)(Bt + (wn + f * 16 + rbase) * 32 + kb);
    }
#pragma unroll
    for (int i = 0; i < 4; ++i)
#pragma unroll
      for (int j = 0; j < 4; ++j)
        acc[i][j] = __builtin_amdgcn_mfma_f32_16x16x32_bf16(af[i], bfr[j],
                                                            acc[i][j], 0, 0, 0);
    __syncthreads();
  }

  // epilogue: D lane mapping col = lane&15, row = (lane>>4)*4 + t
  const int rr = (lane >> 4) * 4, cc = lane & 15;
  float* Cf = (float*)C;
  bf16_t* Cb = (bf16_t*)C;
#pragma unroll
  for (int i = 0; i < 4; ++i) {
#pragma unroll
    for (int j = 0; j < 4; ++j) {
#pragma unroll
      for (int t = 0; t < 4; ++t) {
        const int gr = m0 + wm + i * 16 + rr + t;
        const int gc = n0 + wn + j * 16 + cc;
        float v = acc[i][j][t];
        const size_t idx = (size_t)gr * 4096 + gc;
        if constexpr (EPI == 0) {
          Cb[idx] = __float2bfloat16(v);
        } else if constexpr (EPI == 1) {
          v = fmaxf(v, 0.f) * rowm[gr];
          Cb[idx] = __float2bfloat16(v);
        } else if constexpr (EPI == 2) {
          v = __bfloat162float(X0[idx]) + fmaxf(v, 0.f) * rowm[gr];
          Cb[idx] = __float2bfloat16(v);
        } else {
          v = fmaxf(v + lnb[gc], 0.f);
          Cf[idx] = satt[gr] * v * rowm[gr];
        }
      }
    }
  }
}

// ---------------------------------------------------------------- smalls ----
__global__ void att_kernel(const bf16_t* __restrict__ x,
                           const float* __restrict__ aw,
                           const float* __restrict__ ab,
                           float* __restrict__ satt) {
  const int row = blockIdx.x, tid = threadIdx.x;
  float s = 0.f;
  for (int j = tid; j < 4096; j += 256)
    s += __bfloat162float(x[(size_t)row * 4096 + j]) * aw[j];
  __shared__ float red[256];
  red[tid] = s;
  __syncthreads();
  for (int st = 128; st > 0; st >>= 1) {
    if (tid < st) red[tid] += red[tid + st];
    __syncthreads();
  }
  if (tid == 0) satt[row] = 1.f / (1.f + expf(-(red[0] + ab[0])));
}

__global__ void pool_kernel(const float* __restrict__ g,
                            float* __restrict__ ge) {
  const int c = blockIdx.x * 256 + threadIdx.x;
  const int b = blockIdx.y;
  float s = 0.f, mx = 0.f;  // g >= 0 so max init 0 matches jnp.max
  const float* p = g + (size_t)b * 512 * 4096 + c;
  for (int srow = 0; srow < 512; ++srow) {
    const float v = p[(size_t)srow * 4096];
    s += v;
    mx = fmaxf(mx, v);
  }
  ge[b * 4096 + c] = s * mx;
}

__global__ void final_kernel(const float* __restrict__ ge,
                             const float* __restrict__ pw,
                             const float* __restrict__ pb,
                             float* __restrict__ out) {
  const int b = blockIdx.x, tid = threadIdx.x;
  float a[20];
#pragma unroll
  for (int k = 0; k < 20; ++k) a[k] = 0.f;
  for (int c = tid; c < 4096; c += 256) {
    const float v = ge[b * 4096 + c];
#pragma unroll
    for (int k = 0; k < 20; ++k) a[k] += v * pw[c * 20 + k];
  }
  __shared__ float red[256][20];
#pragma unroll
  for (int k = 0; k < 20; ++k) red[tid][k] = a[k];
  __syncthreads();
  for (int st = 128; st > 0; st >>= 1) {
    if (tid < st)
      for (int k = 0; k < 20; ++k) red[tid][k] += red[tid + st][k];
    __syncthreads();
  }
  if (tid < 20) out[b * 20 + tid] = red[0][tid] + pb[tid];
}

// ---------------------------------------------------------------- launch ----
extern "C" void kernel_launch(void* const* d_in, const int* in_sizes, int n_in,
                              void* d_out, int out_size, void* d_ws,
                              size_t ws_size, hipStream_t stream) {
  const float* inputs = (const float*)d_in[0];
  const float* adj    = (const float*)d_in[1];
  const float* mask   = (const float*)d_in[2];
  const float* W0     = (const float*)d_in[3];
  const float* W1     = (const float*)d_in[4];
  const float* att_w  = (const float*)d_in[5];
  const float* att_b  = (const float*)d_in[6];
  const float* ln_w   = (const float*)d_in[7];
  const float* ln_b   = (const float*)d_in[8];
  const float* pred_w = (const float*)d_in[9];
  const float* pred_b = (const float*)d_in[10];
  float* out = (float*)d_out;

  const size_t MB32 = (size_t)32 * 1024 * 1024;
  char* ws = (char*)d_ws;
  bf16_t* SLOT0 = (bf16_t*)(ws);             // XT -> x0T -> x
  bf16_t* SLOT1 = (bf16_t*)(ws + MB32);      // W0T -> W1T -> ln_wT
  bf16_t* SLOT2 = (bf16_t*)(ws + 2 * MB32);  // adjb -> g(lo)
  bf16_t* SLOT3 = (bf16_t*)(ws + 3 * MB32);  // S0T -> S1T -> g(hi)
  bf16_t* SLOT4 = (bf16_t*)(ws + 4 * MB32);  // x0
  float*  g     = (float*)(ws + 2 * MB32);   // 64MB spanning SLOT2..SLOT3
  float*  satt  = (float*)(ws + 5 * MB32);
  float*  ge    = (float*)(ws + 5 * MB32 + 64 * 1024);
  // total workspace need: 160MB + ~192KB

  const dim3 gT(64, 64), gG(32, 32);

  // M1: S0T = XT (.) W0T     (S0T[j][i] = sum_k X[k][j] W0[k][i])
  transpose_to_bf16<float><<<gT, 256, 0, stream>>>(inputs, SLOT0);
  transpose_to_bf16<float><<<gT, 256, 0, stream>>>(W0, SLOT1);
  convert_f32_to_bf16<<<16384, 256, 0, stream>>>(adj, SLOT2);
  gemm_nt<0><<<gG, 256, 0, stream>>>(SLOT0, SLOT1, SLOT3, nullptr, nullptr,
                                     nullptr, nullptr);
  // M2: x0 = relu(adjb (.) S0T) * mask[row]
  gemm_nt<1><<<gG, 256, 0, stream>>>(SLOT2, SLOT3, SLOT4, nullptr, mask,
                                     nullptr, nullptr);
  // x0T, W1T
  transpose_to_bf16<bf16_t><<<gT, 256, 0, stream>>>(SLOT4, SLOT0);
  transpose_to_bf16<float><<<gT, 256, 0, stream>>>(W1, SLOT1);
  // M3: S1T = x0T (.) W1T
  gemm_nt<0><<<gG, 256, 0, stream>>>(SLOT0, SLOT1, SLOT3, nullptr, nullptr,
                                     nullptr, nullptr);
  // M4: x = x0 + relu(adjb (.) S1T) * mask[row]
  gemm_nt<2><<<gG, 256, 0, stream>>>(SLOT2, SLOT3, SLOT0, SLOT4, mask,
                                     nullptr, nullptr);
  // soft_att from x
  att_kernel<<<4096, 256, 0, stream>>>(SLOT0, att_w, att_b, satt);
  // ln_wT
  transpose_to_bf16<float><<<gT, 256, 0, stream>>>(ln_w, SLOT1);
  // M5: g = satt[r] * relu(x (.) ln_wT + ln_b[c]) * mask[r]   (fp32)
  gemm_nt<3><<<gG, 256, 0, stream>>>(SLOT0, SLOT1, g, nullptr, mask, satt,
                                     ln_b);
  // pool: ge[b][c] = sum_s g * max_s g
  pool_kernel<<<dim3(16, 8), 256, 0, stream>>>(g, ge);
  // out = ge @ pred_w + pred_b
  final_kernel<<<8, 256, 0, stream>>>(ge, pred_w, pred_b, out);
}

// Round 2
// 812.398 us; speedup vs baseline: 1.3028x; 1.3028x over previous
//
#include <hip/hip_runtime.h>
#include <hip/hip_bf16.h>
#include <math.h>

typedef __attribute__((ext_vector_type(8))) short short8;
typedef __attribute__((ext_vector_type(4))) float floatx4;
using bf16_t = __hip_bfloat16;

#define GLOAD16(gp, lp)                                                        \
  __builtin_amdgcn_global_load_lds(                                            \
      (const __attribute__((address_space(1))) unsigned int*)(gp),             \
      (__attribute__((address_space(3))) unsigned int*)(lp), 16, 0, 0)

#define CFENCE() asm volatile("" ::: "memory")
#define BAR()                                                                  \
  do {                                                                         \
    CFENCE();                                                                  \
    __builtin_amdgcn_s_barrier();                                              \
    CFENCE();                                                                  \
  } while (0)

// ---------------------------------------------------------------- converts --
__global__ void convert_f32_to_bf16(const float* __restrict__ in,
                                    bf16_t* __restrict__ out) {
  int i = blockIdx.x * 256 + threadIdx.x;  // 4 elements per thread
  float4 v = ((const float4*)in)[i];
  union { ushort4 u; bf16_t b[4]; } pk;
  pk.b[0] = __float2bfloat16(v.x);
  pk.b[1] = __float2bfloat16(v.y);
  pk.b[2] = __float2bfloat16(v.z);
  pk.b[3] = __float2bfloat16(v.w);
  ((ushort4*)out)[i] = pk.u;
}

// out[c][r] = bf16(in[r][c]), both 4096x4096
template <typename T>
__global__ void transpose_to_bf16(const T* __restrict__ in,
                                  bf16_t* __restrict__ out) {
  __shared__ float tile[64][65];
  const int r0 = blockIdx.y * 64, c0 = blockIdx.x * 64;
  const int tid = threadIdx.x;
  for (int i = tid; i < 64 * 64; i += 256) {
    const int r = i >> 6, c = i & 63;
    float v;
    if constexpr (sizeof(T) == 4)
      v = in[(size_t)(r0 + r) * 4096 + (c0 + c)];
    else
      v = __bfloat162float(in[(size_t)(r0 + r) * 4096 + (c0 + c)]);
    tile[r][c] = v;
  }
  __syncthreads();
  for (int i = tid; i < 64 * 64; i += 256) {
    const int c = i >> 6, r = i & 63;
    out[(size_t)(c0 + c) * 4096 + (r0 + r)] = __float2bfloat16(tile[r][c]);
  }
}

// ---------------------------------------------------------------- NT GEMM ---
// C[m][n] = sum_k A[m][k]*B[n][k]; 4096^3, bf16 K-fastest operands.
// 256x256 tile, BK=32, 8 waves (2Mx4N), 4-deep LDS ring, prefetch dist 3,
// counted vmcnt(12), raw s_barrier, XOR-swizzled LDS (slot ^= (row>>1)&3).
// EPI 0: C=bf16(acc)
// EPI 1: C=bf16(relu(acc)*mask[m])
// EPI 2: C=bf16(X0[m][n] + relu(acc)*mask[m])
// EPI 3: Cf=float( satt[m] * relu(acc+lnb[n]) * mask[m] )
template <int EPI>
__global__ __launch_bounds__(512, 2) void gemm_nt(
    const bf16_t* __restrict__ A, const bf16_t* __restrict__ B,
    void* __restrict__ C, const bf16_t* __restrict__ X0,
    const float* __restrict__ rowm, const float* __restrict__ satt,
    const float* __restrict__ lnb) {
  extern __shared__ bf16_t smem[];  // 4 bufs x (A 8192 + B 8192) = 128 KiB
  const int tid = threadIdx.x;
  const int wave = tid >> 6, lane = tid & 63;
  const int m0 = blockIdx.y * 256, n0 = blockIdx.x * 256;
  const int wmr = (wave >> 2) * 128;  // wave row base (2 waves in M)
  const int wnc = (wave & 3) * 64;    // wave col base (4 waves in N)

  floatx4 acc[8][4] = {};

  // ---- staging addressing (per-thread constants). One GLOAD16 call moves
  // 512thr x 16B = 8KB = 128 rows of 64B; wave w covers rows w*16..w*16+15.
  // LDS dest is linear (wave-uniform base + lane*16); swizzle goes on the
  // GLOBAL source: physical slot (lane&3) holds logical slot ^ ((row>>1)&3).
  const int lr = wave * 16 + (lane >> 2);             // local row in 128-half
  const int sw = (((lane & 3) ^ ((lr >> 1) & 3))) * 8;  // swizzled col elems
  const size_t gA0 = (size_t)(m0 + lr) * 4096 + sw;
  const size_t gA1 = (size_t)(m0 + 128 + lr) * 4096 + sw;
  const size_t gB0 = (size_t)(n0 + lr) * 4096 + sw;
  const size_t gB1 = (size_t)(n0 + 128 + lr) * 4096 + sw;
  const int ldsH0 = (wave * 16) * 32;        // this wave's 1KB chunk, half 0
  const int ldsH1 = (128 + wave * 16) * 32;  // half 1

  // ---- ds_read addressing. Frag m: row = wmr + m*16 + (lane&15),
  // logical slot = lane>>4; physical slot = logical ^ ((row>>1)&3).
  // (row>>1)&3 is invariant across m (m*16 rows), so hoist.
  const int rA = wmr + (lane & 15);
  const int rB = wnc + (lane & 15);
  const int offA = rA * 32 + (((lane >> 4) ^ ((rA >> 1) & 3)) * 8);
  const int offB = rB * 32 + (((lane >> 4) ^ ((rB >> 1) & 3)) * 8);

  // ---- prologue: stage tiles 0,1,2 (12 issues/wave, in order)
  for (int p = 0; p < 3; ++p) {
    bf16_t* sA = smem + p * 16384;
    bf16_t* sB = sA + 8192;
    const size_t ko = (size_t)p * 32;
    GLOAD16(A + gA0 + ko, sA + ldsH0);
    GLOAD16(A + gA1 + ko, sA + ldsH1);
    GLOAD16(B + gB0 + ko, sB + ldsH0);
    GLOAD16(B + gB1 + ko, sB + ldsH1);
  }

  for (int t = 0; t < 128; ++t) {
    {  // stage tile t+3 into buf (t+3)&3 (wraps past K harmlessly)
      const size_t ko = (size_t)((t + 3) & 127) * 32;
      bf16_t* sA = smem + ((t + 3) & 3) * 16384;
      bf16_t* sB = sA + 8192;
      GLOAD16(A + gA0 + ko, sA + ldsH0);
      GLOAD16(A + gA1 + ko, sA + ldsH1);
      GLOAD16(B + gB0 + ko, sB + ldsH0);
      GLOAD16(B + gB1 + ko, sB + ldsH1);
    }
    // newest 12 outstanding = tiles t+1,t+2,t+3 -> tile t complete
    asm volatile("s_waitcnt vmcnt(12)" ::: "memory");
    BAR();  // tile t visible to all waves

    const bf16_t* At = smem + (t & 3) * 16384;
    const bf16_t* Bt = At + 8192;
    short8 aF[8], bF[4];
#pragma unroll
    for (int n = 0; n < 4; ++n) bF[n] = *(const short8*)(Bt + offB + n * 512);
#pragma unroll
    for (int m = 0; m < 8; ++m) aF[m] = *(const short8*)(At + offA + m * 512);
    __builtin_amdgcn_s_setprio(1);
#pragma unroll
    for (int m = 0; m < 8; ++m)
#pragma unroll
      for (int n = 0; n < 4; ++n)
        acc[m][n] = __builtin_amdgcn_mfma_f32_16x16x32_bf16(aF[m], bF[n],
                                                            acc[m][n], 0, 0, 0);
    __builtin_amdgcn_s_setprio(0);
    BAR();  // all waves done reading buf t&3 (next iter overwrites it)
  }
  asm volatile("s_waitcnt vmcnt(0)" ::: "memory");

  // epilogue: D lane mapping col = lane&15, row = (lane>>4)*4 + u
  const int rr = (lane >> 4) * 4, cc = lane & 15;
  float* Cf = (float*)C;
  bf16_t* Cb = (bf16_t*)C;
#pragma unroll
  for (int m = 0; m < 8; ++m) {
#pragma unroll
    for (int n = 0; n < 4; ++n) {
#pragma unroll
      for (int u = 0; u < 4; ++u) {
        const int gr = m0 + wmr + m * 16 + rr + u;
        const int gc = n0 + wnc + n * 16 + cc;
        float v = acc[m][n][u];
        const size_t idx = (size_t)gr * 4096 + gc;
        if constexpr (EPI == 0) {
          Cb[idx] = __float2bfloat16(v);
        } else if constexpr (EPI == 1) {
          v = fmaxf(v, 0.f) * rowm[gr];
          Cb[idx] = __float2bfloat16(v);
        } else if constexpr (EPI == 2) {
          v = __bfloat162float(X0[idx]) + fmaxf(v, 0.f) * rowm[gr];
          Cb[idx] = __float2bfloat16(v);
        } else {
          v = fmaxf(v + lnb[gc], 0.f);
          Cf[idx] = satt[gr] * v * rowm[gr];
        }
      }
    }
  }
}

// ---------------------------------------------------------------- smalls ----
__global__ void att_kernel(const bf16_t* __restrict__ x,
                           const float* __restrict__ aw,
                           const float* __restrict__ ab,
                           float* __restrict__ satt) {
  const int row = blockIdx.x, tid = threadIdx.x;
  float s = 0.f;
  for (int j = tid; j < 4096; j += 256)
    s += __bfloat162float(x[(size_t)row * 4096 + j]) * aw[j];
  __shared__ float red[256];
  red[tid] = s;
  __syncthreads();
  for (int st = 128; st > 0; st >>= 1) {
    if (tid < st) red[tid] += red[tid + st];
    __syncthreads();
  }
  if (tid == 0) satt[row] = 1.f / (1.f + expf(-(red[0] + ab[0])));
}

__global__ void pool_kernel(const float* __restrict__ g,
                            float* __restrict__ ge) {
  const int c = blockIdx.x * 256 + threadIdx.x;
  const int b = blockIdx.y;
  float s = 0.f, mx = 0.f;  // g >= 0 so max init 0 matches jnp.max
  const float* p = g + (size_t)b * 512 * 4096 + c;
  for (int srow = 0; srow < 512; ++srow) {
    const float v = p[(size_t)srow * 4096];
    s += v;
    mx = fmaxf(mx, v);
  }
  ge[b * 4096 + c] = s * mx;
}

__global__ void final_kernel(const float* __restrict__ ge,
                             const float* __restrict__ pw,
                             const float* __restrict__ pb,
                             float* __restrict__ out) {
  const int b = blockIdx.x, tid = threadIdx.x;
  float a[20];
#pragma unroll
  for (int k = 0; k < 20; ++k) a[k] = 0.f;
  for (int c = tid; c < 4096; c += 256) {
    const float v = ge[b * 4096 + c];
#pragma unroll
    for (int k = 0; k < 20; ++k) a[k] += v * pw[c * 20 + k];
  }
  __shared__ float red[256][20];
#pragma unroll
  for (int k = 0; k < 20; ++k) red[tid][k] = a[k];
  __syncthreads();
  for (int st = 128; st > 0; st >>= 1) {
    if (tid < st)
      for (int k = 0; k < 20; ++k) red[tid][k] += red[tid + st][k];
    __syncthreads();
  }
  if (tid < 20) out[b * 20 + tid] = red[0][tid] + pb[tid];
}

// ---------------------------------------------------------------- launch ----
extern "C" void kernel_launch(void* const* d_in, const int* in_sizes, int n_in,
                              void* d_out, int out_size, void* d_ws,
                              size_t ws_size, hipStream_t stream) {
  const float* inputs = (const float*)d_in[0];
  const float* adj    = (const float*)d_in[1];
  const float* mask   = (const float*)d_in[2];
  const float* W0     = (const float*)d_in[3];
  const float* W1     = (const float*)d_in[4];
  const float* att_w  = (const float*)d_in[5];
  const float* att_b  = (const float*)d_in[6];
  const float* ln_w   = (const float*)d_in[7];
  const float* ln_b   = (const float*)d_in[8];
  const float* pred_w = (const float*)d_in[9];
  const float* pred_b = (const float*)d_in[10];
  float* out = (float*)d_out;

  const size_t MB32 = (size_t)32 * 1024 * 1024;
  char* ws = (char*)d_ws;
  bf16_t* SLOT0 = (bf16_t*)(ws);             // XT -> x0T -> x
  bf16_t* SLOT1 = (bf16_t*)(ws + MB32);      // W0T -> W1T -> ln_wT
  bf16_t* SLOT2 = (bf16_t*)(ws + 2 * MB32);  // adjb
  bf16_t* SLOT3 = (bf16_t*)(ws + 3 * MB32);  // S0T -> S1T
  bf16_t* SLOT4 = (bf16_t*)(ws + 4 * MB32);  // x0
  float*  g     = (float*)(ws + 5 * MB32);   // 64MB fp32 gated activations
  float*  satt  = (float*)(ws + 7 * MB32);
  float*  ge    = (float*)(ws + 7 * MB32 + 64 * 1024);
  // total workspace need: 224MB + ~192KB

  const int SMEM = 131072;
  (void)hipFuncSetAttribute((const void*)gemm_nt<0>,
                            hipFuncAttributeMaxDynamicSharedMemorySize, SMEM);
  (void)hipFuncSetAttribute((const void*)gemm_nt<1>,
                            hipFuncAttributeMaxDynamicSharedMemorySize, SMEM);
  (void)hipFuncSetAttribute((const void*)gemm_nt<2>,
                            hipFuncAttributeMaxDynamicSharedMemorySize, SMEM);
  (void)hipFuncSetAttribute((const void*)gemm_nt<3>,
                            hipFuncAttributeMaxDynamicSharedMemorySize, SMEM);

  const dim3 gT(64, 64), gG(16, 16);

  // M1: S0T = XT (.) W0T
  transpose_to_bf16<float><<<gT, 256, 0, stream>>>(inputs, SLOT0);
  transpose_to_bf16<float><<<gT, 256, 0, stream>>>(W0, SLOT1);
  convert_f32_to_bf16<<<16384, 256, 0, stream>>>(adj, SLOT2);
  gemm_nt<0><<<gG, 512, SMEM, stream>>>(SLOT0, SLOT1, SLOT3, nullptr, nullptr,
                                        nullptr, nullptr);
  // M2: x0 = relu(adjb (.) S0T) * mask[row]
  gemm_nt<1><<<gG, 512, SMEM, stream>>>(SLOT2, SLOT3, SLOT4, nullptr, mask,
                                        nullptr, nullptr);
  // x0T, W1T
  transpose_to_bf16<bf16_t><<<gT, 256, 0, stream>>>(SLOT4, SLOT0);
  transpose_to_bf16<float><<<gT, 256, 0, stream>>>(W1, SLOT1);
  // M3: S1T = x0T (.) W1T
  gemm_nt<0><<<gG, 512, SMEM, stream>>>(SLOT0, SLOT1, SLOT3, nullptr, nullptr,
                                        nullptr, nullptr);
  // M4: x = x0 + relu(adjb (.) S1T) * mask[row]
  gemm_nt<2><<<gG, 512, SMEM, stream>>>(SLOT2, SLOT3, SLOT0, SLOT4, mask,
                                        nullptr, nullptr);
  // soft_att from x
  att_kernel<<<4096, 256, 0, stream>>>(SLOT0, att_w, att_b, satt);
  // ln_wT
  transpose_to_bf16<float><<<gT, 256, 0, stream>>>(ln_w, SLOT1);
  // M5: g = satt[r] * relu(x (.) ln_wT + ln_b[c]) * mask[r]   (fp32)
  gemm_nt<3><<<gG, 512, SMEM, stream>>>(SLOT0, SLOT1, g, nullptr, mask, satt,
                                        ln_b);
  // pool: ge[b][c] = sum_s g * max_s g
  pool_kernel<<<dim3(16, 8), 256, 0, stream>>>(g, ge);
  // out = ge @ pred_w + pred_b
  final_kernel<<<8, 256, 0, stream>>>(ge, pred_w, pred_b, out);
}

// Round 3
// 768.375 us; speedup vs baseline: 1.3775x; 1.0573x over previous
//
#include <hip/hip_runtime.h>
#include <hip/hip_bf16.h>
#include <math.h>

typedef __attribute__((ext_vector_type(8))) short short8;
typedef __attribute__((ext_vector_type(4))) float floatx4;
using bf16_t = __hip_bfloat16;

#define GLOAD16(gp, lp)                                                        \
  __builtin_amdgcn_global_load_lds(                                            \
      (const __attribute__((address_space(1))) unsigned int*)(gp),             \
      (__attribute__((address_space(3))) unsigned int*)(lp), 16, 0, 0)

#define CFENCE() asm volatile("" ::: "memory")
#define BAR()                                                                  \
  do {                                                                         \
    CFENCE();                                                                  \
    __builtin_amdgcn_s_barrier();                                              \
    CFENCE();                                                                  \
  } while (0)

// ---------------------------------------------------------------- converts --
__global__ void convert_f32_to_bf16(const float* __restrict__ in,
                                    bf16_t* __restrict__ out) {
  int i = blockIdx.x * 256 + threadIdx.x;  // 4 elements per thread
  float4 v = ((const float4*)in)[i];
  union { ushort4 u; bf16_t b[4]; } pk;
  pk.b[0] = __float2bfloat16(v.x);
  pk.b[1] = __float2bfloat16(v.y);
  pk.b[2] = __float2bfloat16(v.z);
  pk.b[3] = __float2bfloat16(v.w);
  ((ushort4*)out)[i] = pk.u;
}

// out[c][r] = bf16(in[r][c]), both 4096x4096
template <typename T>
__global__ void transpose_to_bf16(const T* __restrict__ in,
                                  bf16_t* __restrict__ out) {
  __shared__ float tile[64][65];
  const int r0 = blockIdx.y * 64, c0 = blockIdx.x * 64;
  const int tid = threadIdx.x;
  for (int i = tid; i < 64 * 64; i += 256) {
    const int r = i >> 6, c = i & 63;
    float v;
    if constexpr (sizeof(T) == 4)
      v = in[(size_t)(r0 + r) * 4096 + (c0 + c)];
    else
      v = __bfloat162float(in[(size_t)(r0 + r) * 4096 + (c0 + c)]);
    tile[r][c] = v;
  }
  __syncthreads();
  for (int i = tid; i < 64 * 64; i += 256) {
    const int c = i >> 6, r = i & 63;
    out[(size_t)(c0 + c) * 4096 + (r0 + r)] = __float2bfloat16(tile[r][c]);
  }
}

// ---------------------------------------------------------------- NT GEMM ---
// C[m][n] = sum_k A[m][k]*B[n][k]; 4096^3, bf16 K-fastest operands.
// 256x256 tile, BK=64 (two kk-32 planes), 8 waves (2Mx4N), 2 LDS buffers of
// {A_kk0,A_kk1,B_kk0,B_kk1} planes (128 KiB total). 4 phases per K-tile:
// {ds_read subtile || 2x global_load_lds prefetch; barrier; lgkmcnt(0);
//  setprio(1); 16 MFMA; setprio(0); barrier}. Plane-granular prefetch:
// kk1(t+1) during p0/p1, kk0(t+2) during p2/p3; one counted vmcnt(4)/iter.
// Pair-XOR swizzle (phys8 = slot8 ^ (pair&7)) -> 2 lanes/16B-slot = free.
// EPI 0: C=bf16(acc)
// EPI 1: C=bf16(relu(acc)*mask[m])
// EPI 2: C=bf16(X0[m][n] + relu(acc)*mask[m])
// EPI 3: Cf=float( satt[m] * relu(acc+lnb[n]) * mask[m] )

#define MM(MB, BF)                                                             \
  BAR();                                                                       \
  asm volatile("s_waitcnt lgkmcnt(0)" ::: "memory");                           \
  __builtin_amdgcn_s_setprio(1);                                               \
  _Pragma("unroll") for (int m_ = 0; m_ < 4; ++m_)                             \
      _Pragma("unroll") for (int n_ = 0; n_ < 4; ++n_)                         \
          acc[(MB) + m_][n_] = __builtin_amdgcn_mfma_f32_16x16x32_bf16(        \
              aF[m_], BF[n_], acc[(MB) + m_][n_], 0, 0, 0);                    \
  __builtin_amdgcn_s_setprio(0);                                               \
  BAR();

#define ITER(T, BC)                                                            \
  {                                                                            \
    const int t_ = (T);                                                        \
    const bf16_t* sAk0 = smem + (BC) * 32768;                                  \
    const bf16_t* sAk1 = sAk0 + 8192;                                          \
    const bf16_t* sBk0 = sAk0 + 16384;                                         \
    const bf16_t* sBk1 = sAk0 + 24576;                                         \
    bf16_t* dA1 = smem + (1 - (BC)) * 32768 + 8192 + wave * 512;               \
    bf16_t* dB1 = smem + (1 - (BC)) * 32768 + 24576 + wave * 512;              \
    bf16_t* dA0 = smem + (BC) * 32768 + wave * 512;                            \
    bf16_t* dB0 = smem + (BC) * 32768 + 16384 + wave * 512;                    \
    const size_t kb1 = (size_t)(((t_ + 1) & 63) * 64 + 32);                    \
    const size_t kb2 = (size_t)(((t_ + 2) & 63) * 64);                         \
    short8 aF[4], bF[4];                                                       \
    /* p0: A kk0 m0-3, B kk0; stage A_kk1(t+1) */                              \
    _Pragma("unroll") for (int n = 0; n < 4; ++n)                              \
        bF[n] = *(const short8*)(sBk0 + offB_e + n * 512);                     \
    _Pragma("unroll") for (int m = 0; m < 4; ++m)                              \
        aF[m] = *(const short8*)(sAk0 + offA_e + m * 512);                     \
    GLOAD16(A + gAc0 + kb1, dA1);                                              \
    GLOAD16(A + gAc1 + kb1, dA1 + 4096);                                       \
    MM(0, bF)                                                                  \
    /* p1: A kk0 m4-7; stage B_kk1(t+1) */                                     \
    _Pragma("unroll") for (int m = 0; m < 4; ++m)                              \
        aF[m] = *(const short8*)(sAk0 + offA_e + (4 + m) * 512);               \
    GLOAD16(B + gBc0 + kb1, dB1);                                              \
    GLOAD16(B + gBc1 + kb1, dB1 + 4096);                                       \
    MM(4, bF)                                                                  \
    /* p2: A kk1 m0-3, B kk1; stage A_kk0(t+2) */                              \
    _Pragma("unroll") for (int n = 0; n < 4; ++n)                              \
        bF[n] = *(const short8*)(sBk1 + offB_e + n * 512);                     \
    _Pragma("unroll") for (int m = 0; m < 4; ++m)                              \
        aF[m] = *(const short8*)(sAk1 + offA_e + m * 512);                     \
    GLOAD16(A + gAc0 + kb2, dA0);                                              \
    GLOAD16(A + gAc1 + kb2, dA0 + 4096);                                       \
    MM(0, bF)                                                                  \
    /* p3: A kk1 m4-7; stage B_kk0(t+2); counted vmcnt(4) */                   \
    _Pragma("unroll") for (int m = 0; m < 4; ++m)                              \
        aF[m] = *(const short8*)(sAk1 + offA_e + (4 + m) * 512);               \
    GLOAD16(B + gBc0 + kb2, dB0);                                              \
    GLOAD16(B + gBc1 + kb2, dB0 + 4096);                                       \
    BAR();                                                                     \
    asm volatile("s_waitcnt lgkmcnt(0)" ::: "memory");                         \
    __builtin_amdgcn_s_setprio(1);                                             \
    _Pragma("unroll") for (int m = 0; m < 4; ++m)                              \
        _Pragma("unroll") for (int n = 0; n < 4; ++n)                          \
            acc[4 + m][n] = __builtin_amdgcn_mfma_f32_16x16x32_bf16(           \
                aF[m], bF[n], acc[4 + m][n], 0, 0, 0);                         \
    __builtin_amdgcn_s_setprio(0);                                             \
    asm volatile("s_waitcnt vmcnt(4)" ::: "memory");                           \
    BAR();                                                                     \
  }

template <int EPI>
__global__ __launch_bounds__(512, 2) void gemm_nt(
    const bf16_t* __restrict__ A, const bf16_t* __restrict__ B,
    void* __restrict__ C, const bf16_t* __restrict__ X0,
    const float* __restrict__ rowm, const float* __restrict__ satt,
    const float* __restrict__ lnb) {
  extern __shared__ bf16_t smem[];  // 2 bufs x 4 planes x 8192 elems = 128 KiB
  const int tid = threadIdx.x;
  const int wave = tid >> 6, lane = tid & 63;
  const int m0 = blockIdx.y * 256, n0 = blockIdx.x * 256;
  const int wr = wave >> 2, wc = wave & 3;  // 2M x 4N wave grid

  floatx4 acc[8][4] = {};

  // ---- staging source addressing (pre-swizzled global; linear LDS dest).
  // Thread tid writes plane elements tid*8..+7 = (pair=tid>>3, phys=tid&7).
  const int pr = tid >> 3, ph = tid & 7;
  const int sl8 = ph ^ (pr & 7);                 // logical slot8
  const int rl = (pr << 1) + (sl8 >> 2);         // local row in 128-row call
  const int colg = (sl8 & 3) << 3;               // k element offset (0..24)
  const size_t gAc0 = (size_t)(m0 + rl) * 4096 + colg;
  const size_t gAc1 = gAc0 + (size_t)128 * 4096;
  const size_t gBc0 = (size_t)(n0 + rl) * 4096 + colg;
  const size_t gBc1 = gBc0 + (size_t)128 * 4096;

  // ---- ds_read addressing: frag (row16 = lane&15, kslot = lane>>4).
  // plane row r: pair = r>>1, rp = r&1; phys8 = (rp*4 + kslot) ^ (pair&7);
  // (pair&7) = (lane&15)>>1 (wave/frag bases are multiples of 8 pairs).
  const int l15 = lane & 15;
  const int phRd = (((lane & 1) << 2) + (lane >> 4)) ^ (l15 >> 1);
  const int offA_e = (wr * 64 + (l15 >> 1)) * 64 + phRd * 8;  // + m*512
  const int offB_e = (wc * 32 + (l15 >> 1)) * 64 + phRd * 8;  // + n*512

  // ---- prologue: kk0(0)->buf0, kk1(0)->buf0, kk0(1)->buf1 (12 calls)
  GLOAD16(A + gAc0, smem + wave * 512);
  GLOAD16(A + gAc1, smem + 4096 + wave * 512);
  GLOAD16(B + gBc0, smem + 16384 + wave * 512);
  GLOAD16(B + gBc1, smem + 16384 + 4096 + wave * 512);
  GLOAD16(A + gAc0 + 32, smem + 8192 + wave * 512);
  GLOAD16(A + gAc1 + 32, smem + 8192 + 4096 + wave * 512);
  GLOAD16(B + gBc0 + 32, smem + 24576 + wave * 512);
  GLOAD16(B + gBc1 + 32, smem + 24576 + 4096 + wave * 512);
  GLOAD16(A + gAc0 + 64, smem + 32768 + wave * 512);
  GLOAD16(A + gAc1 + 64, smem + 32768 + 4096 + wave * 512);
  GLOAD16(B + gBc0 + 64, smem + 32768 + 16384 + wave * 512);
  GLOAD16(B + gBc1 + 64, smem + 32768 + 16384 + 4096 + wave * 512);
  asm volatile("s_waitcnt vmcnt(4)" ::: "memory");
  BAR();

  for (int t = 0; t < 64; t += 2) {
    ITER(t, 0)
    ITER(t + 1, 1)
  }
  asm volatile("s_waitcnt vmcnt(0)" ::: "memory");

  // epilogue: D lane mapping col = lane&15, row = (lane>>4)*4 + u
  const int wmr = wr * 128, wnc = wc * 64;
  const int rr = (lane >> 4) * 4, cc = lane & 15;
  float* Cf = (float*)C;
  bf16_t* Cb = (bf16_t*)C;
#pragma unroll
  for (int m = 0; m < 8; ++m) {
#pragma unroll
    for (int n = 0; n < 4; ++n) {
#pragma unroll
      for (int u = 0; u < 4; ++u) {
        const int gr = m0 + wmr + m * 16 + rr + u;
        const int gc = n0 + wnc + n * 16 + cc;
        float v = acc[m][n][u];
        const size_t idx = (size_t)gr * 4096 + gc;
        if constexpr (EPI == 0) {
          Cb[idx] = __float2bfloat16(v);
        } else if constexpr (EPI == 1) {
          v = fmaxf(v, 0.f) * rowm[gr];
          Cb[idx] = __float2bfloat16(v);
        } else if constexpr (EPI == 2) {
          v = __bfloat162float(X0[idx]) + fmaxf(v, 0.f) * rowm[gr];
          Cb[idx] = __float2bfloat16(v);
        } else {
          v = fmaxf(v + lnb[gc], 0.f);
          Cf[idx] = satt[gr] * v * rowm[gr];
        }
      }
    }
  }
}

// ---------------------------------------------------------------- smalls ----
__global__ void att_kernel(const bf16_t* __restrict__ x,
                           const float* __restrict__ aw,
                           const float* __restrict__ ab,
                           float* __restrict__ satt) {
  const int row = blockIdx.x, tid = threadIdx.x;
  float s = 0.f;
  for (int j = tid; j < 4096; j += 256)
    s += __bfloat162float(x[(size_t)row * 4096 + j]) * aw[j];
  __shared__ float red[256];
  red[tid] = s;
  __syncthreads();
  for (int st = 128; st > 0; st >>= 1) {
    if (tid < st) red[tid] += red[tid + st];
    __syncthreads();
  }
  if (tid == 0) satt[row] = 1.f / (1.f + expf(-(red[0] + ab[0])));
}

__global__ void pool_kernel(const float* __restrict__ g,
                            float* __restrict__ ge) {
  const int c = blockIdx.x * 256 + threadIdx.x;
  const int b = blockIdx.y;
  float s = 0.f, mx = 0.f;  // g >= 0 so max init 0 matches jnp.max
  const float* p = g + (size_t)b * 512 * 4096 + c;
  for (int srow = 0; srow < 512; ++srow) {
    const float v = p[(size_t)srow * 4096];
    s += v;
    mx = fmaxf(mx, v);
  }
  ge[b * 4096 + c] = s * mx;
}

__global__ void final_kernel(const float* __restrict__ ge,
                             const float* __restrict__ pw,
                             const float* __restrict__ pb,
                             float* __restrict__ out) {
  const int b = blockIdx.x, tid = threadIdx.x;
  float a[20];
#pragma unroll
  for (int k = 0; k < 20; ++k) a[k] = 0.f;
  for (int c = tid; c < 4096; c += 256) {
    const float v = ge[b * 4096 + c];
#pragma unroll
    for (int k = 0; k < 20; ++k) a[k] += v * pw[c * 20 + k];
  }
  __shared__ float red[256][20];
#pragma unroll
  for (int k = 0; k < 20; ++k) red[tid][k] = a[k];
  __syncthreads();
  for (int st = 128; st > 0; st >>= 1) {
    if (tid < st)
      for (int k = 0; k < 20; ++k) red[tid][k] += red[tid + st][k];
    __syncthreads();
  }
  if (tid < 20) out[b * 20 + tid] = red[0][tid] + pb[tid];
}

// ---------------------------------------------------------------- launch ----
extern "C" void kernel_launch(void* const* d_in, const int* in_sizes, int n_in,
                              void* d_out, int out_size, void* d_ws,
                              size_t ws_size, hipStream_t stream) {
  const float* inputs = (const float*)d_in[0];
  const float* adj    = (const float*)d_in[1];
  const float* mask   = (const float*)d_in[2];
  const float* W0     = (const float*)d_in[3];
  const float* W1     = (const float*)d_in[4];
  const float* att_w  = (const float*)d_in[5];
  const float* att_b  = (const float*)d_in[6];
  const float* ln_w   = (const float*)d_in[7];
  const float* ln_b   = (const float*)d_in[8];
  const float* pred_w = (const float*)d_in[9];
  const float* pred_b = (const float*)d_in[10];
  float* out = (float*)d_out;

  const size_t MB32 = (size_t)32 * 1024 * 1024;
  char* ws = (char*)d_ws;
  bf16_t* SLOT0 = (bf16_t*)(ws);             // XT -> x0T -> x
  bf16_t* SLOT1 = (bf16_t*)(ws + MB32);      // W0T -> W1T -> ln_wT
  bf16_t* SLOT2 = (bf16_t*)(ws + 2 * MB32);  // adjb
  bf16_t* SLOT3 = (bf16_t*)(ws + 3 * MB32);  // S0T -> S1T
  bf16_t* SLOT4 = (bf16_t*)(ws + 4 * MB32);  // x0
  float*  g     = (float*)(ws + 5 * MB32);   // 64MB fp32 gated activations
  float*  satt  = (float*)(ws + 7 * MB32);
  float*  ge    = (float*)(ws + 7 * MB32 + 64 * 1024);
  // total workspace need: 224MB + ~192KB

  const int SMEM = 131072;
  (void)hipFuncSetAttribute((const void*)gemm_nt<0>,
                            hipFuncAttributeMaxDynamicSharedMemorySize, SMEM);
  (void)hipFuncSetAttribute((const void*)gemm_nt<1>,
                            hipFuncAttributeMaxDynamicSharedMemorySize, SMEM);
  (void)hipFuncSetAttribute((const void*)gemm_nt<2>,
                            hipFuncAttributeMaxDynamicSharedMemorySize, SMEM);
  (void)hipFuncSetAttribute((const void*)gemm_nt<3>,
                            hipFuncAttributeMaxDynamicSharedMemorySize, SMEM);

  const dim3 gT(64, 64), gG(16, 16);

  // M1: S0T = XT (.) W0T
  transpose_to_bf16<float><<<gT, 256, 0, stream>>>(inputs, SLOT0);
  transpose_to_bf16<float><<<gT, 256, 0, stream>>>(W0, SLOT1);
  convert_f32_to_bf16<<<16384, 256, 0, stream>>>(adj, SLOT2);
  gemm_nt<0><<<gG, 512, SMEM, stream>>>(SLOT0, SLOT1, SLOT3, nullptr, nullptr,
                                        nullptr, nullptr);
  // M2: x0 = relu(adjb (.) S0T) * mask[row]
  gemm_nt<1><<<gG, 512, SMEM, stream>>>(SLOT2, SLOT3, SLOT4, nullptr, mask,
                                        nullptr, nullptr);
  // x0T, W1T
  transpose_to_bf16<bf16_t><<<gT, 256, 0, stream>>>(SLOT4, SLOT0);
  transpose_to_bf16<float><<<gT, 256, 0, stream>>>(W1, SLOT1);
  // M3: S1T = x0T (.) W1T
  gemm_nt<0><<<gG, 512, SMEM, stream>>>(SLOT0, SLOT1, SLOT3, nullptr, nullptr,
                                        nullptr, nullptr);
  // M4: x = x0 + relu(adjb (.) S1T) * mask[row]
  gemm_nt<2><<<gG, 512, SMEM, stream>>>(SLOT2, SLOT3, SLOT0, SLOT4, mask,
                                        nullptr, nullptr);
  // soft_att from x
  att_kernel<<<4096, 256, 0, stream>>>(SLOT0, att_w, att_b, satt);
  // ln_wT
  transpose_to_bf16<float><<<gT, 256, 0, stream>>>(ln_w, SLOT1);
  // M5: g = satt[r] * relu(x (.) ln_wT + ln_b[c]) * mask[r]   (fp32)
  gemm_nt<3><<<gG, 512, SMEM, stream>>>(SLOT0, SLOT1, g, nullptr, mask, satt,
                                        ln_b);
  // pool: ge[b][c] = sum_s g * max_s g
  pool_kernel<<<dim3(16, 8), 256, 0, stream>>>(g, ge);
  // out = ge @ pred_w + pred_b
  final_kernel<<<8, 256, 0, stream>>>(ge, pred_w, pred_b, out);
}

// Round 4
// 707.371 us; speedup vs baseline: 1.4963x; 1.0862x over previous
//
#include <hip/hip_runtime.h>
#include <hip/hip_bf16.h>
#include <math.h>

typedef __attribute__((ext_vector_type(8))) short short8;
typedef __attribute__((ext_vector_type(4))) float floatx4;
using bf16_t = __hip_bfloat16;

#define GLOAD16(gp, lp)                                                        \
  __builtin_amdgcn_global_load_lds(                                            \
      (const __attribute__((address_space(1))) unsigned int*)(gp),             \
      (__attribute__((address_space(3))) unsigned int*)(lp), 16, 0, 0)

#define CFENCE() asm volatile("" ::: "memory")
#define BAR()                                                                  \
  do {                                                                         \
    CFENCE();                                                                  \
    __builtin_amdgcn_s_barrier();                                              \
    CFENCE();                                                                  \
  } while (0)

// ---------------------------------------------------------------- converts --
__global__ void convert_f32_to_bf16(const float* __restrict__ in,
                                    bf16_t* __restrict__ out) {
  int i = blockIdx.x * 256 + threadIdx.x;  // 4 elements per thread
  float4 v = ((const float4*)in)[i];
  union { ushort4 u; bf16_t b[4]; } pk;
  pk.b[0] = __float2bfloat16(v.x);
  pk.b[1] = __float2bfloat16(v.y);
  pk.b[2] = __float2bfloat16(v.z);
  pk.b[3] = __float2bfloat16(v.w);
  ((ushort4*)out)[i] = pk.u;
}

// out[c][r] = bf16(in[r][c]), both 4096x4096. float4 loads, ushort4 stores.
__global__ void transpose_f32_bf16(const float* __restrict__ in,
                                   bf16_t* __restrict__ out) {
  __shared__ float t[64][65];
  const int r0 = blockIdx.y * 64, c0 = blockIdx.x * 64;
  const int tid = threadIdx.x;
  const int c4 = tid & 15, rr = tid >> 4;
#pragma unroll
  for (int i = 0; i < 4; ++i) {
    const int r = rr + i * 16;
    float4 v = *(const float4*)(in + (size_t)(r0 + r) * 4096 + c0 + c4 * 4);
    t[c4 * 4 + 0][r] = v.x;
    t[c4 * 4 + 1][r] = v.y;
    t[c4 * 4 + 2][r] = v.z;
    t[c4 * 4 + 3][r] = v.w;
  }
  __syncthreads();
  const int r4 = tid & 15, cc = tid >> 4;
#pragma unroll
  for (int i = 0; i < 4; ++i) {
    const int c = cc + i * 16;
    union { ushort4 u; bf16_t b[4]; } pk;
#pragma unroll
    for (int j = 0; j < 4; ++j) pk.b[j] = __float2bfloat16(t[c][r4 * 4 + j]);
    *(ushort4*)(out + (size_t)(c0 + c) * 4096 + r0 + r4 * 4) = pk.u;
  }
}

// ---------------------------------------------------------------- NT GEMM ---
// C[m][n] = sum_k A[m][k]*B[n][k]; 4096^3, bf16 K-fastest operands.
// 256x256 tile, 8 waves (2Mx4N). LDS: ring of 4 K=32 half-planes per operand
// (4 x 16KB A + 4 x 16KB B = 128 KiB). Per region (one K=32 half):
//   {4x global_load_lds (half r+3) ; 12x ds_read_b128 frags (half r) ;
//    setprio(1) 32 MFMA setprio(0) ; vmcnt(8) ; s_barrier}
// ONE barrier + ONE counted vmcnt per region; compiler inserts fine-grained
// lgkmcnt between ds_reads and MFMAs (no forced lgkmcnt(0) drain).
// Pair-XOR swizzle (phys8 = slot8 ^ (pair&7)) -> conflict-free ds_read_b128.
// EPI 0: C=bf16(acc)
// EPI 2: C=bf16(X0[m][n] + relu(acc)*mask[m])
// EPI 3: Cf=float( satt[m] * relu(acc+lnb[n]) * mask[m] )
// EPI 4: C=bf16(relu(acc)*mask[m]) AND CT = C^T (LDS-staged transpose)

#define REGION(R, S)                                                           \
  {                                                                            \
    const int h3 = ((R) + 3) & 127;                                            \
    const size_t ko = (size_t)h3 * 32;                                         \
    bf16_t* dA = smem + (((R) + 3) & 3) * 8192 + wave * 512;                   \
    bf16_t* dB = smem + 32768 + (((R) + 3) & 3) * 8192 + wave * 512;           \
    GLOAD16(A + gAc0 + ko, dA);                                                \
    GLOAD16(A + gAc1 + ko, dA + 4096);                                         \
    GLOAD16(B + gBc0 + ko, dB);                                                \
    GLOAD16(B + gBc1 + ko, dB + 4096);                                         \
    const bf16_t* sA = smem + (S) * 8192;                                      \
    const bf16_t* sB = smem + 32768 + (S) * 8192;                              \
    short8 aF[8], bF[4];                                                       \
    _Pragma("unroll") for (int n = 0; n < 4; ++n)                              \
        bF[n] = *(const short8*)(sB + offB_e + n * 512);                       \
    _Pragma("unroll") for (int m = 0; m < 8; ++m)                              \
        aF[m] = *(const short8*)(sA + offA_e + m * 512);                       \
    __builtin_amdgcn_s_setprio(1);                                             \
    _Pragma("unroll") for (int m = 0; m < 8; ++m)                              \
        _Pragma("unroll") for (int n = 0; n < 4; ++n)                          \
            acc[m][n] = __builtin_amdgcn_mfma_f32_16x16x32_bf16(               \
                aF[m], bF[n], acc[m][n], 0, 0, 0);                             \
    __builtin_amdgcn_s_setprio(0);                                             \
    asm volatile("s_waitcnt vmcnt(8)" ::: "memory");                           \
    BAR();                                                                     \
  }

template <int EPI>
__global__ __launch_bounds__(512, 2) void gemm_nt(
    const bf16_t* __restrict__ A, const bf16_t* __restrict__ B,
    void* __restrict__ C, bf16_t* __restrict__ CT,
    const bf16_t* __restrict__ X0, const float* __restrict__ rowm,
    const float* __restrict__ satt, const float* __restrict__ lnb) {
  extern __shared__ bf16_t smem[];  // 8 planes x 8192 elems = 128 KiB
  const int tid = threadIdx.x;
  const int wave = tid >> 6, lane = tid & 63;
  const int m0 = blockIdx.y * 256, n0 = blockIdx.x * 256;
  const int wr = wave >> 2, wc = wave & 3;  // 2M x 4N wave grid

  floatx4 acc[8][4] = {};

  // ---- staging source addressing (pre-swizzled global; linear LDS dest).
  const int pr = tid >> 3, ph = tid & 7;
  const int sl8 = ph ^ (pr & 7);                 // logical slot8
  const int rl = (pr << 1) + (sl8 >> 2);         // local row in 128-row call
  const int colg = (sl8 & 3) << 3;               // k element offset (0..24)
  const size_t gAc0 = (size_t)(m0 + rl) * 4096 + colg;
  const size_t gAc1 = gAc0 + (size_t)128 * 4096;
  const size_t gBc0 = (size_t)(n0 + rl) * 4096 + colg;
  const size_t gBc1 = gBc0 + (size_t)128 * 4096;

  // ---- ds_read addressing: frag (row16 = lane&15, kslot = lane>>4).
  const int l15 = lane & 15;
  const int phRd = (((lane & 1) << 2) + (lane >> 4)) ^ (l15 >> 1);
  const int offA_e = (wr * 64 + (l15 >> 1)) * 64 + phRd * 8;  // + m*512
  const int offB_e = (wc * 32 + (l15 >> 1)) * 64 + phRd * 8;  // + n*512

  // ---- prologue: stage halves 0,1,2 into ring slots 0,1,2
#pragma unroll
  for (int p = 0; p < 3; ++p) {
    bf16_t* dA = smem + p * 8192 + wave * 512;
    bf16_t* dB = smem + 32768 + p * 8192 + wave * 512;
    const size_t ko = (size_t)p * 32;
    GLOAD16(A + gAc0 + ko, dA);
    GLOAD16(A + gAc1 + ko, dA + 4096);
    GLOAD16(B + gBc0 + ko, dB);
    GLOAD16(B + gBc1 + ko, dB + 4096);
  }
  asm volatile("s_waitcnt vmcnt(8)" ::: "memory");
  BAR();

  for (int r = 0; r < 128; r += 4) {
    REGION(r, 0)
    REGION(r + 1, 1)
    REGION(r + 2, 2)
    REGION(r + 3, 3)
  }
  asm volatile("s_waitcnt vmcnt(0)" ::: "memory");
  BAR();  // ring LDS now safe to reuse (EPI 4)

  // epilogue: D lane mapping col = lane&15, row = (lane>>4)*4 + u
  const int wmr = wr * 128, wnc = wc * 64;
  const int rr = (lane >> 4) * 4, cc = lane & 15;
  float* Cf = (float*)C;
  bf16_t* Cb = (bf16_t*)C;
  bf16_t* myT = smem + wave * 8192;  // EPI4: 64 cols x 128 rows, XOR-swizzled
#pragma unroll
  for (int m = 0; m < 8; ++m) {
#pragma unroll
    for (int n = 0; n < 4; ++n) {
#pragma unroll
      for (int u = 0; u < 4; ++u) {
        const int gr = m0 + wmr + m * 16 + rr + u;
        const int gc = n0 + wnc + n * 16 + cc;
        float v = acc[m][n][u];
        const size_t idx = (size_t)gr * 4096 + gc;
        if constexpr (EPI == 0) {
          Cb[idx] = __float2bfloat16(v);
        } else if constexpr (EPI == 2) {
          v = __bfloat162float(X0[idx]) + fmaxf(v, 0.f) * rowm[gr];
          Cb[idx] = __float2bfloat16(v);
        } else if constexpr (EPI == 3) {
          v = fmaxf(v + lnb[gc], 0.f);
          Cf[idx] = satt[gr] * v * rowm[gr];
        } else {  // EPI 4: relu*mask, write C and stage C^T in LDS
          v = fmaxf(v, 0.f) * rowm[gr];
          const bf16_t bv = __float2bfloat16(v);
          Cb[idx] = bv;
          const int lrow = m * 16 + rr + u;  // 0..127
          const int lcol = n * 16 + cc;      // 0..63
          myT[lcol * 128 + (lrow ^ ((lcol & 15) << 3))] = bv;
        }
      }
    }
  }
  if constexpr (EPI == 4) {
    // per-wave private region: own writes -> own reads (compiler lgkm waits)
#pragma unroll
    for (int i = 0; i < 16; ++i) {
      const int chunkid = i * 64 + lane;  // 0..1023
      const int lcol = chunkid >> 4;      // 0..63 (feature within wave tile)
      const int a8 = chunkid & 15;        // token chunk
      const int lbase = lcol * 128 + ((a8 * 8) ^ ((lcol & 15) << 3));
      short8 vv = *(const short8*)(myT + lbase);
      *(short8*)(CT + (size_t)(n0 + wnc + lcol) * 4096 + (m0 + wmr) + a8 * 8) =
          vv;
    }
  }
}

// ---------------------------------------------------------------- smalls ----
__global__ void att_kernel(const bf16_t* __restrict__ x,
                           const float* __restrict__ aw,
                           const float* __restrict__ ab,
                           float* __restrict__ satt) {
  const int row = blockIdx.x, tid = threadIdx.x;
  float s = 0.f;
  const bf16_t* xr = x + (size_t)row * 4096 + tid * 16;
#pragma unroll
  for (int h = 0; h < 2; ++h) {
    short8 v = *(const short8*)(xr + h * 8);
#pragma unroll
    for (int j = 0; j < 8; ++j) {
      union { unsigned int u; float f; } cv;
      cv.u = ((unsigned int)(unsigned short)v[j]) << 16;
      s += cv.f * aw[tid * 16 + h * 8 + j];
    }
  }
  __shared__ float red[256];
  red[tid] = s;
  __syncthreads();
  for (int st = 128; st > 0; st >>= 1) {
    if (tid < st) red[tid] += red[tid + st];
    __syncthreads();
  }
  if (tid == 0) satt[row] = 1.f / (1.f + expf(-(red[0] + ab[0])));
}

__global__ void pool_kernel(const float* __restrict__ g,
                            float* __restrict__ ge) {
  const int c = blockIdx.x * 256 + threadIdx.x;
  const int b = blockIdx.y;
  float s = 0.f, mx = 0.f;  // g >= 0 so max init 0 matches jnp.max
  const float* p = g + (size_t)b * 512 * 4096 + c;
  for (int srow = 0; srow < 512; ++srow) {
    const float v = p[(size_t)srow * 4096];
    s += v;
    mx = fmaxf(mx, v);
  }
  ge[b * 4096 + c] = s * mx;
}

__global__ void final_kernel(const float* __restrict__ ge,
                             const float* __restrict__ pw,
                             const float* __restrict__ pb,
                             float* __restrict__ out) {
  const int b = blockIdx.x, tid = threadIdx.x;
  float a[20];
#pragma unroll
  for (int k = 0; k < 20; ++k) a[k] = 0.f;
  for (int c = tid; c < 4096; c += 256) {
    const float v = ge[b * 4096 + c];
#pragma unroll
    for (int k = 0; k < 20; ++k) a[k] += v * pw[c * 20 + k];
  }
  __shared__ float red[256][20];
#pragma unroll
  for (int k = 0; k < 20; ++k) red[tid][k] = a[k];
  __syncthreads();
  for (int st = 128; st > 0; st >>= 1) {
    if (tid < st)
      for (int k = 0; k < 20; ++k) red[tid][k] += red[tid + st][k];
    __syncthreads();
  }
  if (tid < 20) out[b * 20 + tid] = red[0][tid] + pb[tid];
}

// ---------------------------------------------------------------- launch ----
extern "C" void kernel_launch(void* const* d_in, const int* in_sizes, int n_in,
                              void* d_out, int out_size, void* d_ws,
                              size_t ws_size, hipStream_t stream) {
  const float* inputs = (const float*)d_in[0];
  const float* adj    = (const float*)d_in[1];
  const float* mask   = (const float*)d_in[2];
  const float* W0     = (const float*)d_in[3];
  const float* W1     = (const float*)d_in[4];
  const float* att_w  = (const float*)d_in[5];
  const float* att_b  = (const float*)d_in[6];
  const float* ln_w   = (const float*)d_in[7];
  const float* ln_b   = (const float*)d_in[8];
  const float* pred_w = (const float*)d_in[9];
  const float* pred_b = (const float*)d_in[10];
  float* out = (float*)d_out;

  const size_t MB32 = (size_t)32 * 1024 * 1024;
  char* ws = (char*)d_ws;
  bf16_t* SLOT0 = (bf16_t*)(ws);             // XT -> x0T -> x
  bf16_t* SLOT1 = (bf16_t*)(ws + MB32);      // W0T -> W1T -> ln_wT
  bf16_t* SLOT2 = (bf16_t*)(ws + 2 * MB32);  // adjb
  bf16_t* SLOT3 = (bf16_t*)(ws + 3 * MB32);  // S0T -> S1T
  bf16_t* SLOT4 = (bf16_t*)(ws + 4 * MB32);  // x0
  float*  g     = (float*)(ws + 5 * MB32);   // 64MB fp32 gated activations
  float*  satt  = (float*)(ws + 7 * MB32);
  float*  ge    = (float*)(ws + 7 * MB32 + 64 * 1024);

  const int SMEM = 131072;
  (void)hipFuncSetAttribute((const void*)gemm_nt<0>,
                            hipFuncAttributeMaxDynamicSharedMemorySize, SMEM);
  (void)hipFuncSetAttribute((const void*)gemm_nt<2>,
                            hipFuncAttributeMaxDynamicSharedMemorySize, SMEM);
  (void)hipFuncSetAttribute((const void*)gemm_nt<3>,
                            hipFuncAttributeMaxDynamicSharedMemorySize, SMEM);
  (void)hipFuncSetAttribute((const void*)gemm_nt<4>,
                            hipFuncAttributeMaxDynamicSharedMemorySize, SMEM);

  const dim3 gT(64, 64), gG(16, 16);

  // M1: S0T = XT (.) W0T
  transpose_f32_bf16<<<gT, 256, 0, stream>>>(inputs, SLOT0);
  transpose_f32_bf16<<<gT, 256, 0, stream>>>(W0, SLOT1);
  convert_f32_to_bf16<<<16384, 256, 0, stream>>>(adj, SLOT2);
  gemm_nt<0><<<gG, 512, SMEM, stream>>>(SLOT0, SLOT1, SLOT3, nullptr, nullptr,
                                        nullptr, nullptr, nullptr);
  // M2: x0 = relu(adjb (.) S0T) * mask[row]; fused x0T write
  gemm_nt<4><<<gG, 512, SMEM, stream>>>(SLOT2, SLOT3, SLOT4, SLOT0, nullptr,
                                        mask, nullptr, nullptr);
  // W1T
  transpose_f32_bf16<<<gT, 256, 0, stream>>>(W1, SLOT1);
  // M3: S1T = x0T (.) W1T
  gemm_nt<0><<<gG, 512, SMEM, stream>>>(SLOT0, SLOT1, SLOT3, nullptr, nullptr,
                                        nullptr, nullptr, nullptr);
  // M4: x = x0 + relu(adjb (.) S1T) * mask[row]
  gemm_nt<2><<<gG, 512, SMEM, stream>>>(SLOT2, SLOT3, SLOT0, nullptr, SLOT4,
                                        mask, nullptr, nullptr);
  // soft_att from x
  att_kernel<<<4096, 256, 0, stream>>>(SLOT0, att_w, att_b, satt);
  // ln_wT
  transpose_f32_bf16<<<gT, 256, 0, stream>>>(ln_w, SLOT1);
  // M5: g = satt[r] * relu(x (.) ln_wT + ln_b[c]) * mask[r]   (fp32)
  gemm_nt<3><<<gG, 512, SMEM, stream>>>(SLOT0, SLOT1, g, nullptr, nullptr,
                                        mask, satt, ln_b);
  // pool: ge[b][c] = sum_s g * max_s g
  pool_kernel<<<dim3(16, 8), 256, 0, stream>>>(g, ge);
  // out = ge @ pred_w + pred_b
  final_kernel<<<8, 256, 0, stream>>>(ge, pred_w, pred_b, out);
}